// Round 1
// baseline (12916.658 us; speedup 1.0000x reference)
//
#include <hip/hip_runtime.h>
#include <math.h>

// Problem constants (match reference)
#define B_   4096
#define N_   50
#define D_   128
#define DV_  8
#define FS_  4
#define SE_  20
#define TPH_ 64
#define NEGV (-1e9f)
#define G_   8           // batch rows per decode block (was 16)
#define NBLK (B_ / G_)   // 512 blocks -> 2 independent barrier domains per CU

// ---------- fast math helpers (fp32, abs err ~1e-7 — safe for argmax) ----------
__device__ __forceinline__ float frcp_(float x) { return __builtin_amdgcn_rcpf(x); }
__device__ __forceinline__ float ftanh_(float x) {
    float e = __expf(2.f * x);               // inf-safe: x>>0 -> e=inf -> rcp=0 -> 1
    return 1.f - 2.f * frcp_(e + 1.f);
}
__device__ __forceinline__ float fsig_(float x) {
    return frcp_(1.f + __expf(-x));
}
__device__ __forceinline__ float wsum_(float v) {
#pragma unroll
    for (int m = 1; m < 64; m <<= 1) v += __shfl_xor(v, m);
    return v;
}

// ---------- kernel A: e = einsum('de,nbe->bnd', W, cu) + bias  -> [B][N][D] ----------
// (unchanged from previous version)
__global__ __launch_bounds__(256) void proj_kernel(
    const float* __restrict__ W,     // [128][128]
    const float* __restrict__ bias,  // [128]
    const float* __restrict__ cu,    // [N][B][D]
    float* __restrict__ outp)        // [B][N][D] (row r = b*N+n)
{
    __shared__ __align__(16) float scu[20][128];
    __shared__ float sb[128];
    const int tid = threadIdx.x;
    if (tid < 128) sb[tid] = bias[tid];
    const int d  = tid & 127;
    const int rq = tid >> 7;   // 0..1
    const float* wrow = W + d * 128;
    const int r0 = blockIdx.x * 200;
    for (int it = 0; it < 10; ++it) {
        const int rbase = r0 + it * 20;
        __syncthreads();   // protect scu from previous iteration's readers (covers sb too, iter 0)
        for (int i = tid; i < 20 * 128; i += 256) {
            int rr = i >> 7, e = i & 127;
            int r = rbase + rr;
            int b = r / 50, n = r - b * 50;
            scu[rr][e] = cu[((size_t)n * B_ + b) * D_ + e];
        }
        __syncthreads();
        float acc[10];
#pragma unroll
        for (int k = 0; k < 10; ++k) acc[k] = 0.f;
        const int rr0 = rq * 10;
        for (int e = 0; e < 128; e += 4) {
            float4 w4 = *(const float4*)&wrow[e];
#pragma unroll
            for (int k = 0; k < 10; ++k) {
                float4 c4 = *(const float4*)&scu[rr0 + k][e];   // wave-uniform: LDS broadcast
                acc[k] += w4.x * c4.x + w4.y * c4.y + w4.z * c4.z + w4.w * c4.w;
            }
        }
        float bv = sb[d];
#pragma unroll
        for (int k = 0; k < 10; ++k)
            outp[(size_t)(rbase + rr0 + k) * D_ + d] = acc[k] + bv;   // coalesced over d
    }
}

// online-softmax body for the glimpse loop (uses enclosing scope vars)
#define GSTEP(nn, c1, c2) do {                                          \
    float part_ = gv1 * ftanh_(qg1 + (c1)) + gv2 * ftanh_(qg2 + (c2));  \
    float u_ = wsum_(part_);                                            \
    if ((mk >> (nn)) & 1ull) u_ = NEGV;                                 \
    float mn_ = fmaxf(m, u_);                                           \
    float al_ = __expf(m - mn_);                                        \
    float w_  = __expf(u_ - mn_);                                       \
    l  = l * al_ + w_;                                                  \
    a1 = a1 * al_ + w_ * (c1);                                          \
    a2 = a2 * al_ + w_ * (c2);                                          \
    m = mn_;                                                            \
} while (0)

// pointer-score body: coalesced row read, logit kept in lane nn
#define PSTEP(nn, c1, c2) do {                                          \
    float part_ = pva * ftanh_(qpa + (c1)) + pvb * ftanh_(qpb + (c2));  \
    float u_ = wsum_(part_);                                            \
    float tl_ = ((mk >> (nn)) & 1ull) ? NEGV : 10.0f * ftanh_(u_);      \
    logit = (lane == (nn)) ? tl_ : logit;                               \
} while (0)

// ---------- kernel B: persistent 50-step decode, one block = 8 batch rows ----------
__global__ __launch_bounds__(512, 4) void decode_kernel(
    const float* __restrict__ dec_in,     // [B][D]
    const float* __restrict__ h0,
    const float* __restrict__ c0,
    const unsigned char* __restrict__ vmask,  // [B][N] bool bytes
    const int* __restrict__ start_idx,    // [B]
    const float* __restrict__ V,          // [B][N][DV]
    const float* __restrict__ cu,         // [N][B][D]
    const float* __restrict__ start_fea,  // [B][FS]
    const float* __restrict__ W_ih,       // [512][128]
    const float* __restrict__ W_hh,       // [512][128]
    const float* __restrict__ b_ih, const float* __restrict__ b_hh,
    const float* __restrict__ gWq, const float* __restrict__ gbq,
    const float* __restrict__ gv,
    const float* __restrict__ pWq, const float* __restrict__ pbq,
    const float* __restrict__ pv,
    const float* __restrict__ step_table, // [51][20]
    const float* __restrict__ tpW1, const float* __restrict__ tpb1,  // [40][64],[64]
    const float* __restrict__ tpW2, const float* __restrict__ tpb2,  // [64],[1]
    const float* __restrict__ e_g, const float* __restrict__ e_p,    // [B][N][D]
    float* __restrict__ outp)
{
    __shared__ __align__(16) float sH[G_][D_];
    __shared__ __align__(16) float sC[G_][D_];
    __shared__ __align__(16) float sX[G_][D_];
    // sU: 8*512 floats. Gates at sU[g*512+j]; after consumption,
    // qg/qp reuse sU[0:1024) (index g*128+d), gl reuses sU[1024:2048).
    __shared__ __align__(16) float sU[G_ * 512];
    __shared__ float sBias[512];
    __shared__ __align__(16) float sGbq[128];
    __shared__ __align__(16) float sPbq[128];
    __shared__ __align__(16) float sGv[128];
    __shared__ __align__(16) float sPv[128];
    __shared__ float sSF[G_][FS_];
    __shared__ unsigned long long sMaskC[G_];
    __shared__ int sPrev[G_], sLast[G_];

    const int tid = threadIdx.x;   // 0..511
    const int b0  = blockIdx.x * G_;

    // ---- init ----
    for (int i = tid; i < G_ * D_; i += 512) {
        int g = i >> 7, d = i & 127;
        size_t src = (size_t)(b0 + g) * D_ + d;
        sH[g][d] = h0[src];
        sC[g][d] = c0[src];
        sX[g][d] = dec_in[src];
    }
    sBias[tid] = b_ih[tid] + b_hh[tid];
    if (tid < 128) {
        sGbq[tid] = gbq[tid];
        sPbq[tid] = pbq[tid];
        sGv[tid]  = gv[tid];
        sPv[tid]  = pv[tid];
    }
    if (tid < G_ * FS_) {
        int g = tid >> 2, k = tid & 3;
        sSF[g][k] = start_fea[(size_t)(b0 + g) * FS_ + k];
    }
    if (tid < G_) {
        unsigned long long mk = 0ull;
        const unsigned char* mrow = vmask + (size_t)(b0 + tid) * N_;
        for (int n = 0; n < N_; ++n)
            if (mrow[n]) mk |= (1ull << n);
        sMaskC[tid] = mk;
        sPrev[tid]  = 0;
        sLast[tid]  = start_idx[b0 + tid];
    }
    __syncthreads();

    const unsigned long long FULL = (1ull << N_) - 1ull;

    for (int t = 0; t < N_; ++t) {
        // ---- P0: mask update (8 threads; consumed 2+ barriers later) ----
        if (tid < G_) {
            unsigned long long mk = sMaskC[tid];
            if (t > 0) mk |= (1ull << sPrev[tid]);
            if ((mk & FULL) == FULL) mk &= ~(1ull << (N_ - 1));
            sMaskC[tid] = mk;
        }
        // ---- P1: gates = x@W_ih.T + h@W_hh.T + (b_ih+b_hh) ----
        // thread j computes all 8 g -> W rows read exactly once per block per step
        {
            const int j = tid;
            const float* wih = W_ih + (size_t)j * 128;
            const float* whh = W_hh + (size_t)j * 128;
            float acc[G_];
#pragma unroll
            for (int g = 0; g < G_; ++g) acc[g] = 0.f;
            for (int e = 0; e < 128; e += 16) {   // 64B/row per chunk: full L1 line use
                float4 wi[4], wh[4];
#pragma unroll
                for (int q = 0; q < 4; ++q) {
                    wi[q] = *(const float4*)&wih[e + 4 * q];
                    wh[q] = *(const float4*)&whh[e + 4 * q];
                }
#pragma unroll
                for (int g = 0; g < G_; ++g) {
                    const float* xr = &sX[g][e];
                    const float* hr = &sH[g][e];
#pragma unroll
                    for (int q = 0; q < 4; ++q) {
                        float4 x4 = *(const float4*)&xr[4 * q];  // wave-uniform broadcast
                        float4 h4 = *(const float4*)&hr[4 * q];
                        acc[g] += wi[q].x * x4.x + wi[q].y * x4.y + wi[q].z * x4.z + wi[q].w * x4.w
                                + wh[q].x * h4.x + wh[q].y * h4.y + wh[q].z * h4.z + wh[q].w * h4.w;
                    }
                }
            }
            float bb = sBias[j];
#pragma unroll
            for (int g = 0; g < G_; ++g) sU[g * 512 + j] = acc[g] + bb;
        }
        __syncthreads();

        // ---- P2: LSTM pointwise ----
        for (int i = tid; i < G_ * D_; i += 512) {
            int g = i >> 7, d = i & 127;
            float ig = fsig_(sU[g * 512 + d]);
            float fg = fsig_(sU[g * 512 + 128 + d]);
            float gg = ftanh_(sU[g * 512 + 256 + d]);
            float og = fsig_(sU[g * 512 + 384 + d]);
            float c2 = fg * sC[g][d] + ig * gg;
            sC[g][d] = c2;
            sH[g][d] = og * ftanh_(c2);
        }
        __syncthreads();

        // ---- P3: qg = h2 @ gWq.T + gbq  -> sU[g*128+d] ----
        {
            const int d  = tid & 127;
            const int gh = tid >> 7;     // 0..3
            const int g0 = gh * 2;
            const float* wr = gWq + (size_t)d * 128;
            float a0 = 0.f, a1 = 0.f;
            for (int e = 0; e < 128; e += 16) {
                float4 w4[4];
#pragma unroll
                for (int q = 0; q < 4; ++q) w4[q] = *(const float4*)&wr[e + 4 * q];
#pragma unroll
                for (int q = 0; q < 4; ++q) {
                    float4 hA = *(const float4*)&sH[g0][e + 4 * q];
                    float4 hB = *(const float4*)&sH[g0 + 1][e + 4 * q];
                    a0 += w4[q].x * hA.x + w4[q].y * hA.y + w4[q].z * hA.z + w4[q].w * hA.w;
                    a1 += w4[q].x * hB.x + w4[q].y * hB.y + w4[q].z * hB.z + w4[q].w * hB.w;
                }
            }
            sU[g0 * 128 + d]       = a0 + sGbq[d];
            sU[(g0 + 1) * 128 + d] = a1 + sGbq[d];
        }
        __syncthreads();

        // ---- P4: glimpse, online-softmax, single pass over e_g; wave per g, depth-2 prefetch ----
        {
            const int g = tid >> 6;       // 0..7
            const int lane = tid & 63;
            const int b = b0 + g;
            const float qg1 = sU[g * 128 + lane];
            const float qg2 = sU[g * 128 + 64 + lane];
            const float gv1 = sGv[lane], gv2 = sGv[64 + lane];
            const unsigned long long mk = sMaskC[g];
            const float* egb = e_g + (size_t)b * (N_ * D_);
            float m = -__builtin_inff(), l = 0.f, a1 = 0.f, a2 = 0.f;
            float A1 = egb[lane],        A2 = egb[64 + lane];
            float B1 = egb[128 + lane],  B2 = egb[192 + lane];
            for (int n = 0; n < N_; n += 2) {
                float c1 = A1, c2 = A2;
                if (n + 2 < N_) { A1 = egb[(n + 2) * 128 + lane]; A2 = egb[(n + 2) * 128 + 64 + lane]; }
                GSTEP(n, c1, c2);
                c1 = B1; c2 = B2;
                if (n + 3 < N_) { B1 = egb[(n + 3) * 128 + lane]; B2 = egb[(n + 3) * 128 + 64 + lane]; }
                GSTEP(n + 1, c1, c2);
            }
            float inv = 1.f / l;
            sU[1024 + g * 128 + lane]      = a1 * inv;
            sU[1024 + g * 128 + 64 + lane] = a2 * inv;
        }
        __syncthreads();

        // ---- P5: qp = gl @ pWq.T + pbq  -> sU[g*128+d] (qg region dead) ----
        {
            const int d  = tid & 127;
            const int gh = tid >> 7;     // 0..3
            const int g0 = gh * 2;
            const float* wr = pWq + (size_t)d * 128;
            float a0 = 0.f, a1 = 0.f;
            for (int e = 0; e < 128; e += 16) {
                float4 w4[4];
#pragma unroll
                for (int q = 0; q < 4; ++q) w4[q] = *(const float4*)&wr[e + 4 * q];
#pragma unroll
                for (int q = 0; q < 4; ++q) {
                    float4 hA = *(const float4*)&sU[1024 + g0 * 128 + e + 4 * q];
                    float4 hB = *(const float4*)&sU[1024 + (g0 + 1) * 128 + e + 4 * q];
                    a0 += w4[q].x * hA.x + w4[q].y * hA.y + w4[q].z * hA.z + w4[q].w * hA.w;
                    a1 += w4[q].x * hB.x + w4[q].y * hB.y + w4[q].z * hB.z + w4[q].w * hB.w;
                }
            }
            sU[g0 * 128 + d]       = a0 + sPbq[d];
            sU[(g0 + 1) * 128 + d] = a1 + sPbq[d];
        }
        __syncthreads();

        // ---- P6: pointer scores (coalesced n-loop), log_softmax, argmax, MLP, gather ----
        {
            const int g = tid >> 6;       // 0..7
            const int lane = tid & 63;
            const int b = b0 + g;
            const unsigned long long mk = sMaskC[g];
            const float qpa = sU[g * 128 + lane];
            const float qpb = sU[g * 128 + 64 + lane];
            const float pva = sPv[lane], pvb = sPv[64 + lane];
            const float* epb = e_p + (size_t)b * (N_ * D_);
            float logit = -__builtin_inff();
            float A1 = epb[lane],        A2 = epb[64 + lane];
            float B1 = epb[128 + lane],  B2 = epb[192 + lane];
            for (int n = 0; n < N_; n += 2) {
                float c1 = A1, c2 = A2;
                if (n + 2 < N_) { A1 = epb[(n + 2) * 128 + lane]; A2 = epb[(n + 2) * 128 + 64 + lane]; }
                PSTEP(n, c1, c2);
                c1 = B1; c2 = B2;
                if (n + 3 < N_) { B1 = epb[(n + 3) * 128 + lane]; B2 = epb[(n + 3) * 128 + 64 + lane]; }
                PSTEP(n + 1, c1, c2);
            }
            const bool active = lane < N_;
            // log-softmax over lanes
            float mx = logit;
#pragma unroll
            for (int mm = 1; mm < 64; mm <<= 1) mx = fmaxf(mx, __shfl_xor(mx, mm));
            float ex = active ? __expf(logit - mx) : 0.f;
            float s = wsum_(ex);
            float lse = mx + __logf(s);
            if (active)
                __builtin_nontemporal_store(logit - lse,
                    &outp[(size_t)b * (N_ * N_) + t * N_ + lane]);
            // argmax, first-index tie-break (matches jnp.argmax)
            float av = logit; int ai = active ? lane : (N_ - 1);
#pragma unroll
            for (int mm = 1; mm < 64; mm <<= 1) {
                float ov = __shfl_xor(av, mm);
                int   oi = __shfl_xor(ai, mm);
                bool take = (ov > av) || (ov == av && oi < ai);
                av = take ? ov : av;
                ai = take ? oi : ai;
            }
            const int idx = ai;
            // time-prediction MLP: lane = hidden unit j (TPH_ == 64)
            const int lastv = sLast[g];
            const float* Vl = V + ((size_t)b * N_ + lastv) * DV_;
            const float* Vi = V + ((size_t)b * N_ + idx) * DV_;
            float hacc = tpb1[lane];
#pragma unroll
            for (int k = 0; k < 8; ++k)  hacc += Vl[k] * tpW1[k * 64 + lane];
#pragma unroll
            for (int k = 0; k < 8; ++k)  hacc += Vi[k] * tpW1[(8 + k) * 64 + lane];
#pragma unroll
            for (int k = 0; k < 4; ++k)  hacc += sSF[g][k] * tpW1[(16 + k) * 64 + lane];
#pragma unroll
            for (int k = 0; k < 20; ++k) hacc += step_table[t * SE_ + k] * tpW1[(20 + k) * 64 + lane];
            hacc = fmaxf(hacc, 0.f);
            float pred = wsum_(hacc * tpW2[lane]) + tpb2[0];
            // next decoder input x2 = context_update[idx, b]
            const float* xrow = cu + ((size_t)idx * B_ + b) * D_;
            sX[g][lane]      = xrow[lane];
            sX[g][64 + lane] = xrow[64 + lane];
            if (lane == 0) {
                __builtin_nontemporal_store((float)idx,
                    &outp[(size_t)(B_ * N_) * N_ + (size_t)b * N_ + t]);
                __builtin_nontemporal_store(pred,
                    &outp[(size_t)(B_ * N_) * N_ + (size_t)(B_ * N_) + (size_t)b * N_ + t]);
                __builtin_nontemporal_store(pred,
                    &outp[(size_t)(B_ * N_) * N_ + 2 * (size_t)(B_ * N_) + (size_t)b * N_ + t]);
                sPrev[g] = idx;
                sLast[g] = idx;
            }
        }
        __syncthreads();
    }
}

#undef GSTEP
#undef PSTEP

extern "C" void kernel_launch(void* const* d_in, const int* in_sizes, int n_in,
                              void* d_out, int out_size, void* d_ws, size_t ws_size,
                              hipStream_t stream)
{
    const float* dec   = (const float*)d_in[0];
    const float* h0    = (const float*)d_in[1];
    const float* c0    = (const float*)d_in[2];
    const unsigned char* vmask = (const unsigned char*)d_in[3];
    const int*   sidx  = (const int*)d_in[4];
    const float* V     = (const float*)d_in[5];
    // d_in[6] b_E, d_in[7] b_E_abs, d_in[9] H_update: unused by reference
    const float* cu    = (const float*)d_in[8];
    const float* sfea  = (const float*)d_in[10];
    const float* W_ih  = (const float*)d_in[11];
    const float* W_hh  = (const float*)d_in[12];
    const float* b_ih  = (const float*)d_in[13];
    const float* b_hh  = (const float*)d_in[14];
    const float* gWq   = (const float*)d_in[15];
    const float* gbq   = (const float*)d_in[16];
    const float* gWr   = (const float*)d_in[17];
    const float* gbr   = (const float*)d_in[18];
    const float* gv    = (const float*)d_in[19];
    const float* pWq   = (const float*)d_in[20];
    const float* pbq   = (const float*)d_in[21];
    const float* pWr   = (const float*)d_in[22];
    const float* pbr   = (const float*)d_in[23];
    const float* pv    = (const float*)d_in[24];
    const float* stept = (const float*)d_in[25];
    const float* tpW1  = (const float*)d_in[26];
    const float* tpb1  = (const float*)d_in[27];
    const float* tpW2  = (const float*)d_in[28];
    const float* tpb2  = (const float*)d_in[29];

    float* e_g = (float*)d_ws;                       // [B][N][D] fp32
    float* e_p = e_g + (size_t)B_ * N_ * D_;         // needs 2*104.86 MB of ws

    // Precompute fixed attention keys (step-invariant)
    proj_kernel<<<dim3(1024), 256, 0, stream>>>(gWr, gbr, cu, e_g);
    proj_kernel<<<dim3(1024), 256, 0, stream>>>(pWr, pbr, cu, e_p);
    // Persistent 50-step decode: 512 blocks x 512 threads, 8 batch rows/block,
    // 2 independent barrier domains per CU for latency overlap
    decode_kernel<<<dim3(NBLK), 512, 0, stream>>>(
        dec, h0, c0, vmask, sidx, V, cu, sfea,
        W_ih, W_hh, b_ih, b_hh,
        gWq, gbq, gv, pWq, pbq, pv,
        stept, tpW1, tpb1, tpW2, tpb2,
        e_g, e_p, (float*)d_out);
}

// Round 2
// 11479.798 us; speedup vs baseline: 1.1252x; 1.1252x over previous
//
#include <hip/hip_runtime.h>
#include <math.h>

// Problem constants (match reference)
#define B_   4096
#define N_   50
#define D_   128
#define DV_  8
#define FS_  4
#define SE_  20
#define TPH_ 64
#define NEGV (-1e9f)
#define G_   16          // batch rows per decode block (G16 geometry: best measured)
#define NBLK (B_ / G_)   // 256 blocks, 1 per CU

// ---------- fast math helpers (fp32, abs err ~1e-7 — safe for argmax) ----------
__device__ __forceinline__ float frcp_(float x) { return __builtin_amdgcn_rcpf(x); }
__device__ __forceinline__ float ftanh_(float x) {
    float e = __expf(2.f * x);               // inf-safe: x>>0 -> e=inf -> rcp=0 -> 1
    return 1.f - 2.f * frcp_(e + 1.f);
}
__device__ __forceinline__ float fsig_(float x) {
    return frcp_(1.f + __expf(-x));
}
__device__ __forceinline__ float wsum_(float v) {
#pragma unroll
    for (int m = 1; m < 64; m <<= 1) v += __shfl_xor(v, m);
    return v;
}

// ---------- kernel A: e = einsum('de,nbe->bnd', W, cu) + bias  -> [B][N][D] ----------
__global__ __launch_bounds__(256) void proj_kernel(
    const float* __restrict__ W,     // [128][128]
    const float* __restrict__ bias,  // [128]
    const float* __restrict__ cu,    // [N][B][D]
    float* __restrict__ outp)        // [B][N][D] (row r = b*N+n)
{
    __shared__ __align__(16) float scu[20][128];
    __shared__ float sb[128];
    const int tid = threadIdx.x;
    if (tid < 128) sb[tid] = bias[tid];
    const int d  = tid & 127;
    const int rq = tid >> 7;   // 0..1
    const float* wrow = W + d * 128;
    const int r0 = blockIdx.x * 200;
    for (int it = 0; it < 10; ++it) {
        const int rbase = r0 + it * 20;
        __syncthreads();
        for (int i = tid; i < 20 * 128; i += 256) {
            int rr = i >> 7, e = i & 127;
            int r = rbase + rr;
            int b = r / 50, n = r - b * 50;
            scu[rr][e] = cu[((size_t)n * B_ + b) * D_ + e];
        }
        __syncthreads();
        float acc[10];
#pragma unroll
        for (int k = 0; k < 10; ++k) acc[k] = 0.f;
        const int rr0 = rq * 10;
        for (int e = 0; e < 128; e += 4) {
            float4 w4 = *(const float4*)&wrow[e];
#pragma unroll
            for (int k = 0; k < 10; ++k) {
                float4 c4 = *(const float4*)&scu[rr0 + k][e];   // wave-uniform: LDS broadcast
                acc[k] += w4.x * c4.x + w4.y * c4.y + w4.z * c4.z + w4.w * c4.w;
            }
        }
        float bv = sb[d];
#pragma unroll
        for (int k = 0; k < 10; ++k)
            outp[(size_t)(rbase + rr0 + k) * D_ + d] = acc[k] + bv;   // coalesced over d
    }
}

#define PF_ 10   // prefetch ring depth for e_g / e_p streams (covers ~800 cy)

// ---------- kernel B: persistent 50-step decode, one block = 16 batch rows ----------
__global__ __launch_bounds__(1024) void decode_kernel(
    const float* __restrict__ dec_in,     // [B][D]
    const float* __restrict__ h0,
    const float* __restrict__ c0,
    const unsigned char* __restrict__ vmask,  // [B][N] bool bytes
    const int* __restrict__ start_idx,    // [B]
    const float* __restrict__ V,          // [B][N][DV]
    const float* __restrict__ cu,         // [N][B][D]
    const float* __restrict__ start_fea,  // [B][FS]
    const float* __restrict__ W_ih,       // [512][128]
    const float* __restrict__ W_hh,       // [512][128]
    const float* __restrict__ b_ih, const float* __restrict__ b_hh,
    const float* __restrict__ gWq, const float* __restrict__ gbq,
    const float* __restrict__ gv,
    const float* __restrict__ pWq, const float* __restrict__ pbq,
    const float* __restrict__ pv,
    const float* __restrict__ step_table, // [51][20]
    const float* __restrict__ tpW1, const float* __restrict__ tpb1,  // [40][64],[64]
    const float* __restrict__ tpW2, const float* __restrict__ tpb2,  // [64],[1]
    const float* __restrict__ e_g, const float* __restrict__ e_p,    // [B][N][D]
    float* __restrict__ outp)
{
    __shared__ __align__(16) float sH[G_][D_];
    __shared__ __align__(16) float sC[G_][D_];
    __shared__ __align__(16) float sX[G_][D_];
    // sU: 16*512 floats. Gates at sU[g*512+j]; after consumption,
    // qg/qp reuse sU[0:2048) (index g*128+d), gl reuses sU[2048:4096).
    __shared__ __align__(16) float sU[G_ * 512];
    __shared__ float sBias[512];
    __shared__ __align__(16) float sGbq[128];
    __shared__ __align__(16) float sPbq[128];
    __shared__ __align__(16) float sGv[128];
    __shared__ __align__(16) float sPv[128];
    __shared__ float sSF[G_][FS_];
    __shared__ unsigned long long sMaskC[G_];
    __shared__ int sPrev[G_], sLast[G_];

    const int tid = threadIdx.x;
    const int b0  = blockIdx.x * G_;

    // ---- init ----
    for (int i = tid; i < G_ * D_; i += 1024) {
        int g = i >> 7, d = i & 127;
        size_t src = (size_t)(b0 + g) * D_ + d;
        sH[g][d] = h0[src];
        sC[g][d] = c0[src];
        sX[g][d] = dec_in[src];
    }
    if (tid < 512)       sBias[tid]      = b_ih[tid] + b_hh[tid];
    else if (tid < 640)  sGbq[tid - 512] = gbq[tid - 512];
    else if (tid < 768)  sPbq[tid - 640] = pbq[tid - 640];
    else if (tid < 896)  sGv[tid - 768]  = gv[tid - 768];
    else                 sPv[tid - 896]  = pv[tid - 896];
    if (tid < G_ * FS_) {
        int g = tid >> 2, k = tid & 3;
        sSF[g][k] = start_fea[(size_t)(b0 + g) * FS_ + k];
    }
    if (tid < G_) {
        unsigned long long mk = 0ull;
        const unsigned char* mrow = vmask + (size_t)(b0 + tid) * N_;
        for (int n = 0; n < N_; ++n)
            if (mrow[n]) mk |= (1ull << n);
        sMaskC[tid] = mk;
        sPrev[tid]  = 0;
        sLast[tid]  = start_idx[b0 + tid];
    }
    __syncthreads();

    const unsigned long long FULL = (1ull << N_) - 1ull;

    for (int t = 0; t < N_; ++t) {
        // ---- P0: mask update (16 threads; consumed 2+ barriers later) ----
        if (tid < G_) {
            unsigned long long mk = sMaskC[tid];
            if (t > 0) mk |= (1ull << sPrev[tid]);
            if ((mk & FULL) == FULL) mk &= ~(1ull << (N_ - 1));
            sMaskC[tid] = mk;
        }
        // ---- P1: gates = x@W_ih.T + h@W_hh.T + (b_ih+b_hh) ----
        {
            const int j  = tid & 511;
            const int gh = tid >> 9;      // 0/1 -> g halves
            const int gbase = gh * 8;
            const float* wih = W_ih + (size_t)j * 128;
            const float* whh = W_hh + (size_t)j * 128;
            float acc[8];
#pragma unroll
            for (int g = 0; g < 8; ++g) acc[g] = 0.f;
#pragma unroll          // full unroll: all 64 weight float4 loads hoistable above FMA chains
            for (int e = 0; e < 128; e += 16) {
                float4 wi[4], wh[4];
#pragma unroll
                for (int q = 0; q < 4; ++q) {
                    wi[q] = *(const float4*)&wih[e + 4 * q];
                    wh[q] = *(const float4*)&whh[e + 4 * q];
                }
#pragma unroll
                for (int g = 0; g < 8; ++g) {
                    const float* xr = &sX[gbase + g][e];
                    const float* hr = &sH[gbase + g][e];
#pragma unroll
                    for (int q = 0; q < 4; ++q) {
                        float4 x4 = *(const float4*)&xr[4 * q];  // wave-uniform broadcast
                        float4 h4 = *(const float4*)&hr[4 * q];
                        acc[g] += wi[q].x * x4.x + wi[q].y * x4.y + wi[q].z * x4.z + wi[q].w * x4.w
                                + wh[q].x * h4.x + wh[q].y * h4.y + wh[q].z * h4.z + wh[q].w * h4.w;
                    }
                }
            }
            float bb = sBias[j];
#pragma unroll
            for (int g = 0; g < 8; ++g) sU[(gbase + g) * 512 + j] = acc[g] + bb;
        }
        __syncthreads();

        // ---- P2: LSTM pointwise ----
        for (int i = tid; i < G_ * D_; i += 1024) {
            int g = i >> 7, d = i & 127;
            float ig = fsig_(sU[g * 512 + d]);
            float fg = fsig_(sU[g * 512 + 128 + d]);
            float gg = ftanh_(sU[g * 512 + 256 + d]);
            float og = fsig_(sU[g * 512 + 384 + d]);
            float c2 = fg * sC[g][d] + ig * gg;
            sC[g][d] = c2;
            sH[g][d] = og * ftanh_(c2);
        }
        __syncthreads();

        // ---- P3: qg = h2 @ gWq.T + gbq  -> sU[g*128+d] ----
        {
            const int d  = tid & 127;
            const int gh = tid >> 7;     // 0..7
            const int g0 = gh * 2;
            const float* wr = gWq + (size_t)d * 128;
            float a0 = 0.f, a1 = 0.f;
#pragma unroll          // full unroll: hoist all 32 weight float4 loads
            for (int e = 0; e < 128; e += 16) {
                float4 w4[4];
#pragma unroll
                for (int q = 0; q < 4; ++q) w4[q] = *(const float4*)&wr[e + 4 * q];
#pragma unroll
                for (int q = 0; q < 4; ++q) {
                    float4 hA = *(const float4*)&sH[g0][e + 4 * q];
                    float4 hB = *(const float4*)&sH[g0 + 1][e + 4 * q];
                    a0 += w4[q].x * hA.x + w4[q].y * hA.y + w4[q].z * hA.z + w4[q].w * hA.w;
                    a1 += w4[q].x * hB.x + w4[q].y * hB.y + w4[q].z * hB.z + w4[q].w * hB.w;
                }
            }
            sU[g0 * 128 + d]       = a0 + sGbq[d];
            sU[(g0 + 1) * 128 + d] = a1 + sGbq[d];
        }
        __syncthreads();

        // ---- P4: glimpse softmax, single pass, NO max-subtraction ----
        // |u| <= sum|gv| ~ 5  ->  exp(u) always safe in fp32; masked -> w = 0.
        // Ring-PF_ register prefetch (statically indexed via full unroll) covers LLC latency.
        {
            const int g = tid >> 6;       // 0..15
            const int lane = tid & 63;
            const int b = b0 + g;
            const float qg1 = sU[g * 128 + lane];
            const float qg2 = sU[g * 128 + 64 + lane];
            const float gv1 = sGv[lane], gv2 = sGv[64 + lane];
            const unsigned long long mk = sMaskC[g];
            const float* egb = e_g + (size_t)b * (N_ * D_);
            float l = 0.f, a1 = 0.f, a2 = 0.f;
            float r1[PF_], r2[PF_];
#pragma unroll
            for (int p = 0; p < PF_; ++p) {
                r1[p] = egb[p * 128 + lane];
                r2[p] = egb[p * 128 + 64 + lane];
            }
#pragma unroll
            for (int n = 0; n < N_; ++n) {
                const int s = n % PF_;            // static after full unroll
                float c1 = r1[s], c2 = r2[s];
                if (n + PF_ < N_) {
                    r1[s] = egb[(n + PF_) * 128 + lane];
                    r2[s] = egb[(n + PF_) * 128 + 64 + lane];
                }
                float part = gv1 * ftanh_(qg1 + c1) + gv2 * ftanh_(qg2 + c2);
                float u = wsum_(part);
                float w = ((mk >> n) & 1ull) ? 0.f : __expf(u);
                l  += w;
                a1 += w * c1;
                a2 += w * c2;
            }
            float inv = 1.f / l;
            sU[2048 + g * 128 + lane]      = a1 * inv;
            sU[2048 + g * 128 + 64 + lane] = a2 * inv;
        }
        __syncthreads();

        // ---- P5: qp = gl @ pWq.T + pbq  -> sU[g*128+d] (qg region dead) ----
        {
            const int d  = tid & 127;
            const int gh = tid >> 7;
            const int g0 = gh * 2;
            const float* wr = pWq + (size_t)d * 128;
            float a0 = 0.f, a1 = 0.f;
#pragma unroll          // full unroll: hoist all 32 weight float4 loads
            for (int e = 0; e < 128; e += 16) {
                float4 w4[4];
#pragma unroll
                for (int q = 0; q < 4; ++q) w4[q] = *(const float4*)&wr[e + 4 * q];
#pragma unroll
                for (int q = 0; q < 4; ++q) {
                    float4 hA = *(const float4*)&sU[2048 + g0 * 128 + e + 4 * q];
                    float4 hB = *(const float4*)&sU[2048 + (g0 + 1) * 128 + e + 4 * q];
                    a0 += w4[q].x * hA.x + w4[q].y * hA.y + w4[q].z * hA.z + w4[q].w * hA.w;
                    a1 += w4[q].x * hB.x + w4[q].y * hB.y + w4[q].z * hB.z + w4[q].w * hB.w;
                }
            }
            sU[g0 * 128 + d]       = a0 + sPbq[d];
            sU[(g0 + 1) * 128 + d] = a1 + sPbq[d];
        }
        __syncthreads();

        // ---- P6: pointer scores (coalesced, ring-prefetched), log_softmax, argmax, MLP ----
        {
            const int g = tid >> 6;       // 0..15
            const int lane = tid & 63;
            const int b = b0 + g;
            const unsigned long long mk = sMaskC[g];
            const float qpa = sU[g * 128 + lane];
            const float qpb = sU[g * 128 + 64 + lane];
            const float pva = sPv[lane], pvb = sPv[64 + lane];
            const float* epb = e_p + (size_t)b * (N_ * D_);
            float logit = -__builtin_inff();
            float r1[PF_], r2[PF_];
#pragma unroll
            for (int p = 0; p < PF_; ++p) {
                r1[p] = epb[p * 128 + lane];
                r2[p] = epb[p * 128 + 64 + lane];
            }
#pragma unroll
            for (int n = 0; n < N_; ++n) {
                const int s = n % PF_;            // static after full unroll
                float c1 = r1[s], c2 = r2[s];
                if (n + PF_ < N_) {
                    r1[s] = epb[(n + PF_) * 128 + lane];
                    r2[s] = epb[(n + PF_) * 128 + 64 + lane];
                }
                float part = pva * ftanh_(qpa + c1) + pvb * ftanh_(qpb + c2);
                float u = wsum_(part);
                float tl = ((mk >> n) & 1ull) ? NEGV : 10.0f * ftanh_(u);
                logit = (lane == n) ? tl : logit;
            }
            const bool active = lane < N_;
            // log-softmax over lanes
            float mx = logit;
#pragma unroll
            for (int mm = 1; mm < 64; mm <<= 1) mx = fmaxf(mx, __shfl_xor(mx, mm));
            float ex = active ? __expf(logit - mx) : 0.f;
            float s = wsum_(ex);
            float lse = mx + __logf(s);
            if (active)
                __builtin_nontemporal_store(logit - lse,
                    &outp[(size_t)b * (N_ * N_) + t * N_ + lane]);
            // argmax, first-index tie-break (matches jnp.argmax)
            float av = logit; int ai = active ? lane : (N_ - 1);
#pragma unroll
            for (int mm = 1; mm < 64; mm <<= 1) {
                float ov = __shfl_xor(av, mm);
                int   oi = __shfl_xor(ai, mm);
                bool take = (ov > av) || (ov == av && oi < ai);
                av = take ? ov : av;
                ai = take ? oi : ai;
            }
            const int idx = ai;
            // time-prediction MLP: lane = hidden unit j (TPH_ == 64)
            const int lastv = sLast[g];
            const float* Vl = V + ((size_t)b * N_ + lastv) * DV_;
            const float* Vi = V + ((size_t)b * N_ + idx) * DV_;
            float hacc = tpb1[lane];
#pragma unroll
            for (int k = 0; k < 8; ++k)  hacc += Vl[k] * tpW1[k * 64 + lane];
#pragma unroll
            for (int k = 0; k < 8; ++k)  hacc += Vi[k] * tpW1[(8 + k) * 64 + lane];
#pragma unroll
            for (int k = 0; k < 4; ++k)  hacc += sSF[g][k] * tpW1[(16 + k) * 64 + lane];
#pragma unroll
            for (int k = 0; k < 20; ++k) hacc += step_table[t * SE_ + k] * tpW1[(20 + k) * 64 + lane];
            hacc = fmaxf(hacc, 0.f);
            float pred = wsum_(hacc * tpW2[lane]) + tpb2[0];
            // next decoder input x2 = context_update[idx, b]
            const float* xrow = cu + ((size_t)idx * B_ + b) * D_;
            sX[g][lane]      = xrow[lane];
            sX[g][64 + lane] = xrow[64 + lane];
            if (lane == 0) {
                __builtin_nontemporal_store((float)idx,
                    &outp[(size_t)(B_ * N_) * N_ + (size_t)b * N_ + t]);
                __builtin_nontemporal_store(pred,
                    &outp[(size_t)(B_ * N_) * N_ + (size_t)(B_ * N_) + (size_t)b * N_ + t]);
                __builtin_nontemporal_store(pred,
                    &outp[(size_t)(B_ * N_) * N_ + 2 * (size_t)(B_ * N_) + (size_t)b * N_ + t]);
                sPrev[g] = idx;
                sLast[g] = idx;
            }
        }
        __syncthreads();
    }
}

extern "C" void kernel_launch(void* const* d_in, const int* in_sizes, int n_in,
                              void* d_out, int out_size, void* d_ws, size_t ws_size,
                              hipStream_t stream)
{
    const float* dec   = (const float*)d_in[0];
    const float* h0    = (const float*)d_in[1];
    const float* c0    = (const float*)d_in[2];
    const unsigned char* vmask = (const unsigned char*)d_in[3];
    const int*   sidx  = (const int*)d_in[4];
    const float* V     = (const float*)d_in[5];
    // d_in[6] b_E, d_in[7] b_E_abs, d_in[9] H_update: unused by reference
    const float* cu    = (const float*)d_in[8];
    const float* sfea  = (const float*)d_in[10];
    const float* W_ih  = (const float*)d_in[11];
    const float* W_hh  = (const float*)d_in[12];
    const float* b_ih  = (const float*)d_in[13];
    const float* b_hh  = (const float*)d_in[14];
    const float* gWq   = (const float*)d_in[15];
    const float* gbq   = (const float*)d_in[16];
    const float* gWr   = (const float*)d_in[17];
    const float* gbr   = (const float*)d_in[18];
    const float* gv    = (const float*)d_in[19];
    const float* pWq   = (const float*)d_in[20];
    const float* pbq   = (const float*)d_in[21];
    const float* pWr   = (const float*)d_in[22];
    const float* pbr   = (const float*)d_in[23];
    const float* pv    = (const float*)d_in[24];
    const float* stept = (const float*)d_in[25];
    const float* tpW1  = (const float*)d_in[26];
    const float* tpb1  = (const float*)d_in[27];
    const float* tpW2  = (const float*)d_in[28];
    const float* tpb2  = (const float*)d_in[29];

    float* e_g = (float*)d_ws;                       // [B][N][D] fp32
    float* e_p = e_g + (size_t)B_ * N_ * D_;         // needs 2*104.86 MB of ws

    // Precompute fixed attention keys (step-invariant)
    proj_kernel<<<dim3(1024), 256, 0, stream>>>(gWr, gbr, cu, e_g);
    proj_kernel<<<dim3(1024), 256, 0, stream>>>(pWr, pbr, cu, e_p);
    // Persistent 50-step decode: 256 blocks x 1024 threads, 16 batch rows/block
    decode_kernel<<<dim3(NBLK), 1024, 0, stream>>>(
        dec, h0, c0, vmask, sidx, V, cu, sfea,
        W_ih, W_hh, b_ih, b_hh,
        gWq, gbq, gv, pWq, pbq, pv,
        stept, tpW1, tpb1, tpW2, tpb2,
        e_g, e_p, (float*)d_out);
}

// Round 3
// 7378.054 us; speedup vs baseline: 1.7507x; 1.5559x over previous
//
#include <hip/hip_runtime.h>
#include <math.h>

// Problem constants (match reference)
#define B_   4096
#define N_   50
#define D_   128
#define DV_  8
#define FS_  4
#define SE_  20
#define TPH_ 64
#define NEGV (-1e9f)
#define G_   16          // batch rows per decode block
#define NBLK (B_ / G_)   // 256 blocks, 1 per CU

// ---------- fast math helpers (fp32, abs err ~1e-7 — safe for argmax) ----------
__device__ __forceinline__ float frcp_(float x) { return __builtin_amdgcn_rcpf(x); }
__device__ __forceinline__ float ftanh_(float x) {
    float e = __expf(2.f * x);               // inf-safe: x>>0 -> e=inf -> rcp=0 -> 1
    return 1.f - 2.f * frcp_(e + 1.f);
}
__device__ __forceinline__ float fsig_(float x) {
    return frcp_(1.f + __expf(-x));
}
__device__ __forceinline__ float wsum_(float v) {
#pragma unroll
    for (int m = 1; m < 64; m <<= 1) v += __shfl_xor(v, m);
    return v;
}

// ---------- kernel A: e = einsum('de,nbe->bnd', W, cu) + bias  -> [B][N][D] ----------
__global__ __launch_bounds__(256) void proj_kernel(
    const float* __restrict__ W,     // [128][128]
    const float* __restrict__ bias,  // [128]
    const float* __restrict__ cu,    // [N][B][D]
    float* __restrict__ outp)        // [B][N][D] (row r = b*N+n)
{
    __shared__ __align__(16) float scu[20][128];
    __shared__ float sb[128];
    const int tid = threadIdx.x;
    if (tid < 128) sb[tid] = bias[tid];
    const int d  = tid & 127;
    const int rq = tid >> 7;   // 0..1
    const float* wrow = W + d * 128;
    const int r0 = blockIdx.x * 200;
    for (int it = 0; it < 10; ++it) {
        const int rbase = r0 + it * 20;
        __syncthreads();
        for (int i = tid; i < 20 * 128; i += 256) {
            int rr = i >> 7, e = i & 127;
            int r = rbase + rr;
            int b = r / 50, n = r - b * 50;
            scu[rr][e] = cu[((size_t)n * B_ + b) * D_ + e];
        }
        __syncthreads();
        float acc[10];
#pragma unroll
        for (int k = 0; k < 10; ++k) acc[k] = 0.f;
        const int rr0 = rq * 10;
        for (int e = 0; e < 128; e += 4) {
            float4 w4 = *(const float4*)&wrow[e];
#pragma unroll
            for (int k = 0; k < 10; ++k) {
                float4 c4 = *(const float4*)&scu[rr0 + k][e];   // wave-uniform: LDS broadcast
                acc[k] += w4.x * c4.x + w4.y * c4.y + w4.z * c4.z + w4.w * c4.w;
            }
        }
        float bv = sb[d];
#pragma unroll
        for (int k = 0; k < 10; ++k)
            outp[(size_t)(rbase + rr0 + k) * D_ + d] = acc[k] + bv;   // coalesced over d
    }
}

// ---------- kernel T: out[c][r] = in[r][c]  (tiny, run once) ----------
__global__ __launch_bounds__(256) void transpose_kernel(
    const float* __restrict__ in, float* __restrict__ out, int R, int C)
{
    int idx = blockIdx.x * 256 + threadIdx.x;
    if (idx < R * C) {
        int r = idx / C, c = idx - r * C;
        out[c * R + r] = in[idx];     // coalesced read, scattered write; matrix is tiny
    }
}

#define PF_ 10   // prefetch ring depth for e_g / e_p streams

// ---------- kernel B: persistent 50-step decode, one block = 16 batch rows ----------
// __launch_bounds__(1024, 4): 16 waves/CU = 4 waves/EU -> VGPR cap 128 (was 64) so the
// prefetch rings and weight pipelining can allocate.
__global__ __launch_bounds__(1024, 4) void decode_kernel(
    const float* __restrict__ dec_in,     // [B][D]
    const float* __restrict__ h0,
    const float* __restrict__ c0,
    const unsigned char* __restrict__ vmask,  // [B][N] bool bytes
    const int* __restrict__ start_idx,    // [B]
    const float* __restrict__ V,          // [B][N][DV]
    const float* __restrict__ cu,         // [N][B][D]
    const float* __restrict__ start_fea,  // [B][FS]
    const float* __restrict__ W_ih,       // [512][128]
    const float* __restrict__ W_hh,       // [512][128]
    const float* __restrict__ b_ih, const float* __restrict__ b_hh,
    const float* __restrict__ gWq, const float* __restrict__ gbq,
    const float* __restrict__ gv,
    const float* __restrict__ pWq, const float* __restrict__ pbq,
    const float* __restrict__ pv,
    const float* __restrict__ step_table, // [51][20]
    const float* __restrict__ tpW1, const float* __restrict__ tpb1,  // [40][64],[64]
    const float* __restrict__ tpW2, const float* __restrict__ tpb2,  // [64],[1]
    const float* __restrict__ e_g, const float* __restrict__ e_p,    // [B][N][D]
    const float* __restrict__ wtI,        // [128][512] = W_ih^T (valid iff use_t)
    const float* __restrict__ wtH,        // [128][512] = W_hh^T
    const float* __restrict__ gqT,        // [128][128] = gWq^T
    const float* __restrict__ pqT,        // [128][128] = pWq^T
    const int use_t,
    float* __restrict__ outp)
{
    __shared__ __align__(16) float sH[G_][D_];
    __shared__ __align__(16) float sC[G_][D_];
    __shared__ __align__(16) float sX[G_][D_];
    // sU: 16*512 floats. Gates at sU[g*512+j]; after consumption,
    // qg/qp reuse sU[0:2048) (index g*128+d), gl reuses sU[2048:4096).
    __shared__ __align__(16) float sU[G_ * 512];
    __shared__ __align__(16) float sP2[G_ * 512];   // e-high partial sums (use_t path)
    __shared__ float sBias[512];
    __shared__ __align__(16) float sGbq[128];
    __shared__ __align__(16) float sPbq[128];
    __shared__ __align__(16) float sGv[128];
    __shared__ __align__(16) float sPv[128];
    __shared__ float sSF[G_][FS_];
    __shared__ unsigned long long sMaskC[G_];
    __shared__ int sPrev[G_], sLast[G_];

    const int tid = threadIdx.x;
    const int b0  = blockIdx.x * G_;

    // ---- init ----
    for (int i = tid; i < G_ * D_; i += 1024) {
        int g = i >> 7, d = i & 127;
        size_t src = (size_t)(b0 + g) * D_ + d;
        sH[g][d] = h0[src];
        sC[g][d] = c0[src];
        sX[g][d] = dec_in[src];
    }
    if (tid < 512)       sBias[tid]      = b_ih[tid] + b_hh[tid];
    else if (tid < 640)  sGbq[tid - 512] = gbq[tid - 512];
    else if (tid < 768)  sPbq[tid - 640] = pbq[tid - 640];
    else if (tid < 896)  sGv[tid - 768]  = gv[tid - 768];
    else                 sPv[tid - 896]  = pv[tid - 896];
    if (tid < G_ * FS_) {
        int g = tid >> 2, k = tid & 3;
        sSF[g][k] = start_fea[(size_t)(b0 + g) * FS_ + k];
    }
    if (tid < G_) {
        unsigned long long mk = 0ull;
        const unsigned char* mrow = vmask + (size_t)(b0 + tid) * N_;
        for (int n = 0; n < N_; ++n)
            if (mrow[n]) mk |= (1ull << n);
        sMaskC[tid] = mk;
        sPrev[tid]  = 0;
        sLast[tid]  = start_idx[b0 + tid];
    }
    __syncthreads();

    const unsigned long long FULL = (1ull << N_) - 1ull;

    for (int t = 0; t < N_; ++t) {
        // ---- P0: mask update (16 threads; consumed 2+ barriers later) ----
        if (tid < G_) {
            unsigned long long mk = sMaskC[tid];
            if (t > 0) mk |= (1ull << sPrev[tid]);
            if ((mk & FULL) == FULL) mk &= ~(1ull << (N_ - 1));
            sMaskC[tid] = mk;
        }
        // ---- P1: gates = x@W_ih.T + h@W_hh.T + (b_ih+b_hh) ----
        if (use_t) {
            // Transposed weights: lane-adjacent j -> every weight load coalesced (256 B).
            // Thread = (j, e-half); 16 g accumulators; halves combined in P2 via sP2.
            const int j  = tid & 511;
            const int eh = tid >> 9;              // 0/1
            const int ebase = eh * 64;
            const float* wI = wtI + j;            // stride 512 floats per e
            const float* wH = wtH + j;
            float acc[16];
#pragma unroll
            for (int g = 0; g < 16; ++g) acc[g] = 0.f;
#pragma unroll 2
            for (int ec = 0; ec < 64; ec += 4) {
                const int e = ebase + ec;
                float wi0 = wI[(size_t)(e + 0) * 512], wi1 = wI[(size_t)(e + 1) * 512];
                float wi2 = wI[(size_t)(e + 2) * 512], wi3 = wI[(size_t)(e + 3) * 512];
                float wh0 = wH[(size_t)(e + 0) * 512], wh1 = wH[(size_t)(e + 1) * 512];
                float wh2 = wH[(size_t)(e + 2) * 512], wh3 = wH[(size_t)(e + 3) * 512];
#pragma unroll
                for (int g = 0; g < 16; ++g) {
                    float4 x4 = *(const float4*)&sX[g][e];   // wave-uniform LDS broadcast
                    float4 h4 = *(const float4*)&sH[g][e];
                    acc[g] += wi0 * x4.x + wi1 * x4.y + wi2 * x4.z + wi3 * x4.w
                            + wh0 * h4.x + wh1 * h4.y + wh2 * h4.z + wh3 * h4.w;
                }
            }
            if (eh == 0) {
                float bb = sBias[j];
#pragma unroll
                for (int g = 0; g < 16; ++g) sU[g * 512 + j] = acc[g] + bb;
            } else {
#pragma unroll
                for (int g = 0; g < 16; ++g) sP2[g * 512 + j] = acc[g];
            }
        } else {
            // Fallback (original row-gather path)
            const int j  = tid & 511;
            const int gh = tid >> 9;
            const int gbase = gh * 8;
            const float* wih = W_ih + (size_t)j * 128;
            const float* whh = W_hh + (size_t)j * 128;
            float acc[8];
#pragma unroll
            for (int g = 0; g < 8; ++g) acc[g] = 0.f;
            for (int e = 0; e < 128; e += 16) {
                float4 wi[4], wh[4];
#pragma unroll
                for (int q = 0; q < 4; ++q) {
                    wi[q] = *(const float4*)&wih[e + 4 * q];
                    wh[q] = *(const float4*)&whh[e + 4 * q];
                }
#pragma unroll
                for (int g = 0; g < 8; ++g) {
                    const float* xr = &sX[gbase + g][e];
                    const float* hr = &sH[gbase + g][e];
#pragma unroll
                    for (int q = 0; q < 4; ++q) {
                        float4 x4 = *(const float4*)&xr[4 * q];
                        float4 h4 = *(const float4*)&hr[4 * q];
                        acc[g] += wi[q].x * x4.x + wi[q].y * x4.y + wi[q].z * x4.z + wi[q].w * x4.w
                                + wh[q].x * h4.x + wh[q].y * h4.y + wh[q].z * h4.z + wh[q].w * h4.w;
                    }
                }
            }
            float bb = sBias[j];
#pragma unroll
            for (int g = 0; g < 8; ++g) sU[(gbase + g) * 512 + j] = acc[g] + bb;
        }
        __syncthreads();

        // ---- P2: LSTM pointwise (sums the two e-halves when use_t) ----
        for (int i = tid; i < G_ * D_; i += 1024) {
            int g = i >> 7, d = i & 127;
            float u0 = sU[g * 512 + d],       u1 = sU[g * 512 + 128 + d];
            float u2 = sU[g * 512 + 256 + d], u3 = sU[g * 512 + 384 + d];
            if (use_t) {
                u0 += sP2[g * 512 + d];       u1 += sP2[g * 512 + 128 + d];
                u2 += sP2[g * 512 + 256 + d]; u3 += sP2[g * 512 + 384 + d];
            }
            float ig = fsig_(u0);
            float fg = fsig_(u1);
            float gg = ftanh_(u2);
            float og = fsig_(u3);
            float c2 = fg * sC[g][d] + ig * gg;
            sC[g][d] = c2;
            sH[g][d] = og * ftanh_(c2);
        }
        __syncthreads();

        // ---- P3: qg = h2 @ gWq.T + gbq  -> sU[g*128+d] ----
        if (use_t) {
            const int d  = tid & 127;
            const int gh = tid >> 7;     // 0..7
            const int g0 = gh * 2;
            const float* wq = gqT + d;   // stride 128 floats per e; lane-coalesced
            float a0 = 0.f, a1 = 0.f;
#pragma unroll 4
            for (int e = 0; e < 128; e += 4) {
                float w0 = wq[(e + 0) * 128], w1 = wq[(e + 1) * 128];
                float w2 = wq[(e + 2) * 128], w3 = wq[(e + 3) * 128];
                float4 hA = *(const float4*)&sH[g0][e];
                float4 hB = *(const float4*)&sH[g0 + 1][e];
                a0 += w0 * hA.x + w1 * hA.y + w2 * hA.z + w3 * hA.w;
                a1 += w0 * hB.x + w1 * hB.y + w2 * hB.z + w3 * hB.w;
            }
            sU[g0 * 128 + d]       = a0 + sGbq[d];
            sU[(g0 + 1) * 128 + d] = a1 + sGbq[d];
        } else {
            const int d  = tid & 127;
            const int gh = tid >> 7;
            const int g0 = gh * 2;
            const float* wr = gWq + (size_t)d * 128;
            float a0 = 0.f, a1 = 0.f;
            for (int e = 0; e < 128; e += 16) {
                float4 w4[4];
#pragma unroll
                for (int q = 0; q < 4; ++q) w4[q] = *(const float4*)&wr[e + 4 * q];
#pragma unroll
                for (int q = 0; q < 4; ++q) {
                    float4 hA = *(const float4*)&sH[g0][e + 4 * q];
                    float4 hB = *(const float4*)&sH[g0 + 1][e + 4 * q];
                    a0 += w4[q].x * hA.x + w4[q].y * hA.y + w4[q].z * hA.z + w4[q].w * hA.w;
                    a1 += w4[q].x * hB.x + w4[q].y * hB.y + w4[q].z * hB.z + w4[q].w * hB.w;
                }
            }
            sU[g0 * 128 + d]       = a0 + sGbq[d];
            sU[(g0 + 1) * 128 + d] = a1 + sGbq[d];
        }
        __syncthreads();

        // ---- P4: glimpse softmax, single pass, no max-subtraction ----
        // |u| <= sum|gv| ~ 5 -> exp(u) safe in fp32; masked -> w = 0.
        {
            const int g = tid >> 6;       // 0..15
            const int lane = tid & 63;
            const int b = b0 + g;
            const float qg1 = sU[g * 128 + lane];
            const float qg2 = sU[g * 128 + 64 + lane];
            const float gv1 = sGv[lane], gv2 = sGv[64 + lane];
            const unsigned long long mk = sMaskC[g];
            const float* egb = e_g + (size_t)b * (N_ * D_);
            float l = 0.f, a1 = 0.f, a2 = 0.f;
            float r1[PF_], r2[PF_];
#pragma unroll
            for (int p = 0; p < PF_; ++p) {
                r1[p] = egb[p * 128 + lane];
                r2[p] = egb[p * 128 + 64 + lane];
            }
#pragma unroll
            for (int n = 0; n < N_; ++n) {
                const int s = n % PF_;            // static after full unroll
                float c1 = r1[s], c2 = r2[s];
                if (n + PF_ < N_) {
                    r1[s] = egb[(n + PF_) * 128 + lane];
                    r2[s] = egb[(n + PF_) * 128 + 64 + lane];
                }
                float part = gv1 * ftanh_(qg1 + c1) + gv2 * ftanh_(qg2 + c2);
                float u = wsum_(part);
                float w = ((mk >> n) & 1ull) ? 0.f : __expf(u);
                l  += w;
                a1 += w * c1;
                a2 += w * c2;
            }
            float inv = 1.f / l;
            sU[2048 + g * 128 + lane]      = a1 * inv;
            sU[2048 + g * 128 + 64 + lane] = a2 * inv;
        }
        __syncthreads();

        // ---- P5: qp = gl @ pWq.T + pbq  -> sU[g*128+d] (qg region dead) ----
        if (use_t) {
            const int d  = tid & 127;
            const int gh = tid >> 7;
            const int g0 = gh * 2;
            const float* wq = pqT + d;
            float a0 = 0.f, a1 = 0.f;
#pragma unroll 4
            for (int e = 0; e < 128; e += 4) {
                float w0 = wq[(e + 0) * 128], w1 = wq[(e + 1) * 128];
                float w2 = wq[(e + 2) * 128], w3 = wq[(e + 3) * 128];
                float4 hA = *(const float4*)&sU[2048 + g0 * 128 + e];
                float4 hB = *(const float4*)&sU[2048 + (g0 + 1) * 128 + e];
                a0 += w0 * hA.x + w1 * hA.y + w2 * hA.z + w3 * hA.w;
                a1 += w0 * hB.x + w1 * hB.y + w2 * hB.z + w3 * hB.w;
            }
            sU[g0 * 128 + d]       = a0 + sPbq[d];
            sU[(g0 + 1) * 128 + d] = a1 + sPbq[d];
        } else {
            const int d  = tid & 127;
            const int gh = tid >> 7;
            const int g0 = gh * 2;
            const float* wr = pWq + (size_t)d * 128;
            float a0 = 0.f, a1 = 0.f;
            for (int e = 0; e < 128; e += 16) {
                float4 w4[4];
#pragma unroll
                for (int q = 0; q < 4; ++q) w4[q] = *(const float4*)&wr[e + 4 * q];
#pragma unroll
                for (int q = 0; q < 4; ++q) {
                    float4 hA = *(const float4*)&sU[2048 + g0 * 128 + e + 4 * q];
                    float4 hB = *(const float4*)&sU[2048 + (g0 + 1) * 128 + e + 4 * q];
                    a0 += w4[q].x * hA.x + w4[q].y * hA.y + w4[q].z * hA.z + w4[q].w * hA.w;
                    a1 += w4[q].x * hB.x + w4[q].y * hB.y + w4[q].z * hB.z + w4[q].w * hB.w;
                }
            }
            sU[g0 * 128 + d]       = a0 + sPbq[d];
            sU[(g0 + 1) * 128 + d] = a1 + sPbq[d];
        }
        __syncthreads();

        // ---- P6: pointer scores (coalesced, ring-prefetched), log_softmax, argmax, MLP ----
        {
            const int g = tid >> 6;       // 0..15
            const int lane = tid & 63;
            const int b = b0 + g;
            const unsigned long long mk = sMaskC[g];
            const float qpa = sU[g * 128 + lane];
            const float qpb = sU[g * 128 + 64 + lane];
            const float pva = sPv[lane], pvb = sPv[64 + lane];
            const float* epb = e_p + (size_t)b * (N_ * D_);
            float logit = -__builtin_inff();
            float r1[PF_], r2[PF_];
#pragma unroll
            for (int p = 0; p < PF_; ++p) {
                r1[p] = epb[p * 128 + lane];
                r2[p] = epb[p * 128 + 64 + lane];
            }
#pragma unroll
            for (int n = 0; n < N_; ++n) {
                const int s = n % PF_;            // static after full unroll
                float c1 = r1[s], c2 = r2[s];
                if (n + PF_ < N_) {
                    r1[s] = epb[(n + PF_) * 128 + lane];
                    r2[s] = epb[(n + PF_) * 128 + 64 + lane];
                }
                float part = pva * ftanh_(qpa + c1) + pvb * ftanh_(qpb + c2);
                float u = wsum_(part);
                float tl = ((mk >> n) & 1ull) ? NEGV : 10.0f * ftanh_(u);
                logit = (lane == n) ? tl : logit;
            }
            const bool active = lane < N_;
            // log-softmax over lanes
            float mx = logit;
#pragma unroll
            for (int mm = 1; mm < 64; mm <<= 1) mx = fmaxf(mx, __shfl_xor(mx, mm));
            float ex = active ? __expf(logit - mx) : 0.f;
            float s = wsum_(ex);
            float lse = mx + __logf(s);
            if (active)
                __builtin_nontemporal_store(logit - lse,
                    &outp[(size_t)b * (N_ * N_) + t * N_ + lane]);
            // argmax, first-index tie-break (matches jnp.argmax)
            float av = logit; int ai = active ? lane : (N_ - 1);
#pragma unroll
            for (int mm = 1; mm < 64; mm <<= 1) {
                float ov = __shfl_xor(av, mm);
                int   oi = __shfl_xor(ai, mm);
                bool take = (ov > av) || (ov == av && oi < ai);
                av = take ? ov : av;
                ai = take ? oi : ai;
            }
            const int idx = ai;
            // time-prediction MLP: lane = hidden unit j (TPH_ == 64)
            const int lastv = sLast[g];
            const float* Vl = V + ((size_t)b * N_ + lastv) * DV_;
            const float* Vi = V + ((size_t)b * N_ + idx) * DV_;
            float hacc = tpb1[lane];
#pragma unroll
            for (int k = 0; k < 8; ++k)  hacc += Vl[k] * tpW1[k * 64 + lane];
#pragma unroll
            for (int k = 0; k < 8; ++k)  hacc += Vi[k] * tpW1[(8 + k) * 64 + lane];
#pragma unroll
            for (int k = 0; k < 4; ++k)  hacc += sSF[g][k] * tpW1[(16 + k) * 64 + lane];
#pragma unroll
            for (int k = 0; k < 20; ++k) hacc += step_table[t * SE_ + k] * tpW1[(20 + k) * 64 + lane];
            hacc = fmaxf(hacc, 0.f);
            float pred = wsum_(hacc * tpW2[lane]) + tpb2[0];
            // next decoder input x2 = context_update[idx, b]
            const float* xrow = cu + ((size_t)idx * B_ + b) * D_;
            sX[g][lane]      = xrow[lane];
            sX[g][64 + lane] = xrow[64 + lane];
            if (lane == 0) {
                __builtin_nontemporal_store((float)idx,
                    &outp[(size_t)(B_ * N_) * N_ + (size_t)b * N_ + t]);
                __builtin_nontemporal_store(pred,
                    &outp[(size_t)(B_ * N_) * N_ + (size_t)(B_ * N_) + (size_t)b * N_ + t]);
                __builtin_nontemporal_store(pred,
                    &outp[(size_t)(B_ * N_) * N_ + 2 * (size_t)(B_ * N_) + (size_t)b * N_ + t]);
                sPrev[g] = idx;
                sLast[g] = idx;
            }
        }
        __syncthreads();
    }
}

extern "C" void kernel_launch(void* const* d_in, const int* in_sizes, int n_in,
                              void* d_out, int out_size, void* d_ws, size_t ws_size,
                              hipStream_t stream)
{
    const float* dec   = (const float*)d_in[0];
    const float* h0    = (const float*)d_in[1];
    const float* c0    = (const float*)d_in[2];
    const unsigned char* vmask = (const unsigned char*)d_in[3];
    const int*   sidx  = (const int*)d_in[4];
    const float* V     = (const float*)d_in[5];
    // d_in[6] b_E, d_in[7] b_E_abs, d_in[9] H_update: unused by reference
    const float* cu    = (const float*)d_in[8];
    const float* sfea  = (const float*)d_in[10];
    const float* W_ih  = (const float*)d_in[11];
    const float* W_hh  = (const float*)d_in[12];
    const float* b_ih  = (const float*)d_in[13];
    const float* b_hh  = (const float*)d_in[14];
    const float* gWq   = (const float*)d_in[15];
    const float* gbq   = (const float*)d_in[16];
    const float* gWr   = (const float*)d_in[17];
    const float* gbr   = (const float*)d_in[18];
    const float* gv    = (const float*)d_in[19];
    const float* pWq   = (const float*)d_in[20];
    const float* pbq   = (const float*)d_in[21];
    const float* pWr   = (const float*)d_in[22];
    const float* pbr   = (const float*)d_in[23];
    const float* pv    = (const float*)d_in[24];
    const float* stept = (const float*)d_in[25];
    const float* tpW1  = (const float*)d_in[26];
    const float* tpb1  = (const float*)d_in[27];
    const float* tpW2  = (const float*)d_in[28];
    const float* tpb2  = (const float*)d_in[29];

    const size_t EG = (size_t)B_ * N_ * D_;          // 26,214,400 floats
    float* e_g = (float*)d_ws;
    float* e_p = e_g + EG;

    // Transposed weights appended after e_p (needs +640 KB of ws)
    float* wtI = e_p + EG;
    float* wtH = wtI + 512 * 128;
    float* gqT = wtH + 512 * 128;
    float* pqT = gqT + 128 * 128;
    const size_t need = (2 * EG + 2 * (512 * 128) + 2 * (128 * 128)) * sizeof(float);
    const int use_t = (ws_size >= need) ? 1 : 0;

    // Precompute fixed attention keys (step-invariant)
    proj_kernel<<<dim3(1024), 256, 0, stream>>>(gWr, gbr, cu, e_g);
    proj_kernel<<<dim3(1024), 256, 0, stream>>>(pWr, pbr, cu, e_p);
    if (use_t) {
        transpose_kernel<<<dim3(256), 256, 0, stream>>>(W_ih, wtI, 512, 128);
        transpose_kernel<<<dim3(256), 256, 0, stream>>>(W_hh, wtH, 512, 128);
        transpose_kernel<<<dim3(64),  256, 0, stream>>>(gWq,  gqT, 128, 128);
        transpose_kernel<<<dim3(64),  256, 0, stream>>>(pWq,  pqT, 128, 128);
    }
    // Persistent 50-step decode: 256 blocks x 1024 threads, 16 batch rows/block
    decode_kernel<<<dim3(NBLK), 1024, 0, stream>>>(
        dec, h0, c0, vmask, sidx, V, cu, sfea,
        W_ih, W_hh, b_ih, b_hh,
        gWq, gbq, gv, pWq, pbq, pv,
        stept, tpW1, tpb1, tpW2, tpb2,
        e_g, e_p, wtI, wtH, gqT, pqT, use_t, (float*)d_out);
}

// Round 4
// 7158.064 us; speedup vs baseline: 1.8045x; 1.0307x over previous
//
#include <hip/hip_runtime.h>
#include <math.h>

// Problem constants (match reference)
#define B_   4096
#define N_   50
#define D_   128
#define DV_  8
#define FS_  4
#define SE_  20
#define TPH_ 64
#define NEGV (-1e9f)
#define G_   16          // batch rows per decode block
#define NBLK (B_ / G_)   // 256 blocks, 1 per CU

// ---------- fast math helpers (fp32, abs err ~1e-7 — safe for argmax) ----------
__device__ __forceinline__ float frcp_(float x) { return __builtin_amdgcn_rcpf(x); }
__device__ __forceinline__ float ftanh_(float x) {
    float e = __expf(2.f * x);               // inf-safe: x>>0 -> e=inf -> rcp=0 -> 1
    return 1.f - 2.f * frcp_(e + 1.f);
}
__device__ __forceinline__ float fsig_(float x) {
    return frcp_(1.f + __expf(-x));
}
__device__ __forceinline__ float wsum_(float v) {
#pragma unroll
    for (int m = 1; m < 64; m <<= 1) v += __shfl_xor(v, m);
    return v;
}

// ---------- kernel A: e = einsum('de,nbe->bnd', W, cu) + bias  -> [B][N][D] ----------
__global__ __launch_bounds__(256) void proj_kernel(
    const float* __restrict__ W,     // [128][128]
    const float* __restrict__ bias,  // [128]
    const float* __restrict__ cu,    // [N][B][D]
    float* __restrict__ outp)        // [B][N][D] (row r = b*N+n)
{
    __shared__ __align__(16) float scu[20][128];
    __shared__ float sb[128];
    const int tid = threadIdx.x;
    if (tid < 128) sb[tid] = bias[tid];
    const int d  = tid & 127;
    const int rq = tid >> 7;   // 0..1
    const float* wrow = W + d * 128;
    const int r0 = blockIdx.x * 200;
    for (int it = 0; it < 10; ++it) {
        const int rbase = r0 + it * 20;
        __syncthreads();
        for (int i = tid; i < 20 * 128; i += 256) {
            int rr = i >> 7, e = i & 127;
            int r = rbase + rr;
            int b = r / 50, n = r - b * 50;
            scu[rr][e] = cu[((size_t)n * B_ + b) * D_ + e];
        }
        __syncthreads();
        float acc[10];
#pragma unroll
        for (int k = 0; k < 10; ++k) acc[k] = 0.f;
        const int rr0 = rq * 10;
        for (int e = 0; e < 128; e += 4) {
            float4 w4 = *(const float4*)&wrow[e];
#pragma unroll
            for (int k = 0; k < 10; ++k) {
                float4 c4 = *(const float4*)&scu[rr0 + k][e];   // wave-uniform: LDS broadcast
                acc[k] += w4.x * c4.x + w4.y * c4.y + w4.z * c4.z + w4.w * c4.w;
            }
        }
        float bv = sb[d];
#pragma unroll
        for (int k = 0; k < 10; ++k)
            outp[(size_t)(rbase + rr0 + k) * D_ + d] = acc[k] + bv;   // coalesced over d
    }
}

// ---------- kernel T: out[c][r] = in[r][c]  (tiny, run once) ----------
__global__ __launch_bounds__(256) void transpose_kernel(
    const float* __restrict__ in, float* __restrict__ out, int R, int C)
{
    int idx = blockIdx.x * 256 + threadIdx.x;
    if (idx < R * C) {
        int r = idx / C, c = idx - r * C;
        out[c * R + r] = in[idx];     // coalesced read, scattered write; matrix is tiny
    }
}

#define NB4_ 13   // ceil(N_/4) n-blocks of 4 rows

// ---------- kernel B: persistent 50-step decode, one block = 16 batch rows ----------
// __launch_bounds__(1024, 4): 16 waves/CU -> VGPR cap 128.
__global__ __launch_bounds__(1024, 4) void decode_kernel(
    const float* __restrict__ dec_in,     // [B][D]
    const float* __restrict__ h0,
    const float* __restrict__ c0,
    const unsigned char* __restrict__ vmask,  // [B][N] bool bytes
    const int* __restrict__ start_idx,    // [B]
    const float* __restrict__ V,          // [B][N][DV]
    const float* __restrict__ cu,         // [N][B][D]
    const float* __restrict__ start_fea,  // [B][FS]
    const float* __restrict__ W_ih,       // [512][128]
    const float* __restrict__ W_hh,       // [512][128]
    const float* __restrict__ b_ih, const float* __restrict__ b_hh,
    const float* __restrict__ gWq, const float* __restrict__ gbq,
    const float* __restrict__ gv,
    const float* __restrict__ pWq, const float* __restrict__ pbq,
    const float* __restrict__ pv,
    const float* __restrict__ step_table, // [51][20]
    const float* __restrict__ tpW1, const float* __restrict__ tpb1,  // [40][64],[64]
    const float* __restrict__ tpW2, const float* __restrict__ tpb2,  // [64],[1]
    const float* __restrict__ e_g, const float* __restrict__ e_p,    // [B][N][D]
    const float* __restrict__ wtI,        // [128][512] = W_ih^T (valid iff use_t)
    const float* __restrict__ wtH,        // [128][512] = W_hh^T
    const float* __restrict__ gqT,        // [128][128] = gWq^T
    const float* __restrict__ pqT,        // [128][128] = pWq^T
    const int use_t,
    float* __restrict__ outp)
{
    __shared__ __align__(16) float sH[G_][D_];
    __shared__ __align__(16) float sC[G_][D_];
    __shared__ __align__(16) float sX[G_][D_];
    // sU: 16*512 floats. Gates at sU[g*512+j]; after consumption,
    // qg/qp reuse sU[0:2048) (index g*128+d), gl reuses sU[2048:4096).
    __shared__ __align__(16) float sU[G_ * 512];
    __shared__ __align__(16) float sP2[G_ * 512];   // e-high partial sums (use_t path)
    __shared__ float sBias[512];
    __shared__ __align__(16) float sGbq[128];
    __shared__ __align__(16) float sPbq[128];
    __shared__ __align__(16) float sGv[128];
    __shared__ __align__(16) float sPv[128];
    __shared__ float sSF[G_][FS_];
    __shared__ float sLg[G_][64];                   // pointer logits staging (lane=n regather)
    __shared__ unsigned long long sMaskC[G_];
    __shared__ int sPrev[G_], sLast[G_];

    const int tid = threadIdx.x;
    const int b0  = blockIdx.x * G_;

    // ---- init ----
    for (int i = tid; i < G_ * D_; i += 1024) {
        int g = i >> 7, d = i & 127;
        size_t src = (size_t)(b0 + g) * D_ + d;
        sH[g][d] = h0[src];
        sC[g][d] = c0[src];
        sX[g][d] = dec_in[src];
    }
    if (tid < 512)       sBias[tid]      = b_ih[tid] + b_hh[tid];
    else if (tid < 640)  sGbq[tid - 512] = gbq[tid - 512];
    else if (tid < 768)  sPbq[tid - 640] = pbq[tid - 640];
    else if (tid < 896)  sGv[tid - 768]  = gv[tid - 768];
    else                 sPv[tid - 896]  = pv[tid - 896];
    if (tid < G_ * FS_) {
        int g = tid >> 2, k = tid & 3;
        sSF[g][k] = start_fea[(size_t)(b0 + g) * FS_ + k];
    }
    if (tid < G_) {
        unsigned long long mk = 0ull;
        const unsigned char* mrow = vmask + (size_t)(b0 + tid) * N_;
        for (int n = 0; n < N_; ++n)
            if (mrow[n]) mk |= (1ull << n);
        sMaskC[tid] = mk;
        sPrev[tid]  = 0;
        sLast[tid]  = start_idx[b0 + tid];
    }
    __syncthreads();

    const unsigned long long FULL = (1ull << N_) - 1ull;

    for (int t = 0; t < N_; ++t) {
        // ---- P0: mask update (16 threads; consumed 2+ barriers later) ----
        if (tid < G_) {
            unsigned long long mk = sMaskC[tid];
            if (t > 0) mk |= (1ull << sPrev[tid]);
            if ((mk & FULL) == FULL) mk &= ~(1ull << (N_ - 1));
            sMaskC[tid] = mk;
        }
        // ---- P1: gates = x@W_ih.T + h@W_hh.T + (b_ih+b_hh) ----
        if (use_t) {
            const int j  = tid & 511;
            const int eh = tid >> 9;              // 0/1
            const int ebase = eh * 64;
            const float* wI = wtI + j;            // stride 512 floats per e
            const float* wH = wtH + j;
            float acc[16];
#pragma unroll
            for (int g = 0; g < 16; ++g) acc[g] = 0.f;
#pragma unroll 2
            for (int ec = 0; ec < 64; ec += 4) {
                const int e = ebase + ec;
                float wi0 = wI[(size_t)(e + 0) * 512], wi1 = wI[(size_t)(e + 1) * 512];
                float wi2 = wI[(size_t)(e + 2) * 512], wi3 = wI[(size_t)(e + 3) * 512];
                float wh0 = wH[(size_t)(e + 0) * 512], wh1 = wH[(size_t)(e + 1) * 512];
                float wh2 = wH[(size_t)(e + 2) * 512], wh3 = wH[(size_t)(e + 3) * 512];
#pragma unroll
                for (int g = 0; g < 16; ++g) {
                    float4 x4 = *(const float4*)&sX[g][e];   // wave-uniform LDS broadcast
                    float4 h4 = *(const float4*)&sH[g][e];
                    acc[g] += wi0 * x4.x + wi1 * x4.y + wi2 * x4.z + wi3 * x4.w
                            + wh0 * h4.x + wh1 * h4.y + wh2 * h4.z + wh3 * h4.w;
                }
            }
            if (eh == 0) {
                float bb = sBias[j];
#pragma unroll
                for (int g = 0; g < 16; ++g) sU[g * 512 + j] = acc[g] + bb;
            } else {
#pragma unroll
                for (int g = 0; g < 16; ++g) sP2[g * 512 + j] = acc[g];
            }
        } else {
            const int j  = tid & 511;
            const int gh = tid >> 9;
            const int gbase = gh * 8;
            const float* wih = W_ih + (size_t)j * 128;
            const float* whh = W_hh + (size_t)j * 128;
            float acc[8];
#pragma unroll
            for (int g = 0; g < 8; ++g) acc[g] = 0.f;
            for (int e = 0; e < 128; e += 16) {
                float4 wi[4], wh[4];
#pragma unroll
                for (int q = 0; q < 4; ++q) {
                    wi[q] = *(const float4*)&wih[e + 4 * q];
                    wh[q] = *(const float4*)&whh[e + 4 * q];
                }
#pragma unroll
                for (int g = 0; g < 8; ++g) {
                    const float* xr = &sX[gbase + g][e];
                    const float* hr = &sH[gbase + g][e];
#pragma unroll
                    for (int q = 0; q < 4; ++q) {
                        float4 x4 = *(const float4*)&xr[4 * q];
                        float4 h4 = *(const float4*)&hr[4 * q];
                        acc[g] += wi[q].x * x4.x + wi[q].y * x4.y + wi[q].z * x4.z + wi[q].w * x4.w
                                + wh[q].x * h4.x + wh[q].y * h4.y + wh[q].z * h4.z + wh[q].w * h4.w;
                    }
                }
            }
            float bb = sBias[j];
#pragma unroll
            for (int g = 0; g < 8; ++g) sU[(gbase + g) * 512 + j] = acc[g] + bb;
        }
        __syncthreads();

        // ---- P2: LSTM pointwise (sums the two e-halves when use_t) ----
        for (int i = tid; i < G_ * D_; i += 1024) {
            int g = i >> 7, d = i & 127;
            float u0 = sU[g * 512 + d],       u1 = sU[g * 512 + 128 + d];
            float u2 = sU[g * 512 + 256 + d], u3 = sU[g * 512 + 384 + d];
            if (use_t) {
                u0 += sP2[g * 512 + d];       u1 += sP2[g * 512 + 128 + d];
                u2 += sP2[g * 512 + 256 + d]; u3 += sP2[g * 512 + 384 + d];
            }
            float ig = fsig_(u0);
            float fg = fsig_(u1);
            float gg = ftanh_(u2);
            float og = fsig_(u3);
            float c2 = fg * sC[g][d] + ig * gg;
            sC[g][d] = c2;
            sH[g][d] = og * ftanh_(c2);
        }
        __syncthreads();

        // identities for the wave-per-g phases (P4/P6) and their prefetches
        const int gW   = tid >> 6;        // 0..15
        const int lane = tid & 63;
        const int nq   = lane >> 4;       // 0..3  (row within 4-row block)
        const int dh   = lane & 15;       // 0..15 (8-d chunk)
        const float* egb = e_g + (size_t)(b0 + gW) * (N_ * D_) + dh * 8;
        const float* epb = e_p + (size_t)(b0 + gW) * (N_ * D_) + dh * 8;

        // ---- P3: qg GEMV (+ e_g prefetch for P4 issued first, hides LLC latency) ----
        float4 pgA0 = *(const float4*)&egb[(size_t)nq * 128];
        float4 pgB0 = *(const float4*)&egb[(size_t)nq * 128 + 4];
        float4 pgA1 = *(const float4*)&egb[(size_t)(4 + nq) * 128];
        float4 pgB1 = *(const float4*)&egb[(size_t)(4 + nq) * 128 + 4];
        if (use_t) {
            const int d  = tid & 127;
            const int gh = tid >> 7;     // 0..7
            const int g0 = gh * 2;
            const float* wq = gqT + d;   // stride 128 floats per e; lane-coalesced
            float a0 = 0.f, a1 = 0.f;
#pragma unroll 4
            for (int e = 0; e < 128; e += 4) {
                float w0 = wq[(e + 0) * 128], w1 = wq[(e + 1) * 128];
                float w2 = wq[(e + 2) * 128], w3 = wq[(e + 3) * 128];
                float4 hA = *(const float4*)&sH[g0][e];
                float4 hB = *(const float4*)&sH[g0 + 1][e];
                a0 += w0 * hA.x + w1 * hA.y + w2 * hA.z + w3 * hA.w;
                a1 += w0 * hB.x + w1 * hB.y + w2 * hB.z + w3 * hB.w;
            }
            sU[g0 * 128 + d]       = a0 + sGbq[d];
            sU[(g0 + 1) * 128 + d] = a1 + sGbq[d];
        } else {
            const int d  = tid & 127;
            const int gh = tid >> 7;
            const int g0 = gh * 2;
            const float* wr = gWq + (size_t)d * 128;
            float a0 = 0.f, a1 = 0.f;
            for (int e = 0; e < 128; e += 16) {
                float4 w4[4];
#pragma unroll
                for (int q = 0; q < 4; ++q) w4[q] = *(const float4*)&wr[e + 4 * q];
#pragma unroll
                for (int q = 0; q < 4; ++q) {
                    float4 hA = *(const float4*)&sH[g0][e + 4 * q];
                    float4 hB = *(const float4*)&sH[g0 + 1][e + 4 * q];
                    a0 += w4[q].x * hA.x + w4[q].y * hA.y + w4[q].z * hA.z + w4[q].w * hA.w;
                    a1 += w4[q].x * hB.x + w4[q].y * hB.y + w4[q].z * hB.z + w4[q].w * hB.w;
                }
            }
            sU[g0 * 128 + d]       = a0 + sGbq[d];
            sU[(g0 + 1) * 128 + d] = a1 + sGbq[d];
        }
        __syncthreads();

        // ---- P4: glimpse softmax, 4 rows per wave-iteration ----
        // lane=(nq,dh): 8 d's of row n=blk*4+nq per lane; 4-level shfl per 4 rows.
        // No max-subtraction: |u| <= sum|gv| ~ 5 -> exp safe; masked -> w=0.
        {
            const unsigned long long mk = sMaskC[gW];
            float qgv[8], gvv[8];
            *(float4*)&qgv[0] = *(const float4*)&sU[gW * 128 + dh * 8];
            *(float4*)&qgv[4] = *(const float4*)&sU[gW * 128 + dh * 8 + 4];
            *(float4*)&gvv[0] = *(const float4*)&sGv[dh * 8];
            *(float4*)&gvv[4] = *(const float4*)&sGv[dh * 8 + 4];
            float l = 0.f;
            float a[8];
#pragma unroll
            for (int j = 0; j < 8; ++j) a[j] = 0.f;
#pragma unroll
            for (int blk = 0; blk < NB4_; ++blk) {
                const int n = blk * 4 + nq;
                const int nn = (n < N_) ? n : (N_ - 1);   // clamp: valid read, w forced 0
                float4 cA, cB;
                if (blk == 0)      { cA = pgA0; cB = pgB0; }
                else if (blk == 1) { cA = pgA1; cB = pgB1; }
                else {
                    cA = *(const float4*)&egb[(size_t)nn * 128];
                    cB = *(const float4*)&egb[(size_t)nn * 128 + 4];
                }
                float c[8] = {cA.x, cA.y, cA.z, cA.w, cB.x, cB.y, cB.z, cB.w};
                float part = 0.f;
#pragma unroll
                for (int j = 0; j < 8; ++j) part += gvv[j] * ftanh_(qgv[j] + c[j]);
                part += __shfl_xor(part, 1);
                part += __shfl_xor(part, 2);
                part += __shfl_xor(part, 4);
                part += __shfl_xor(part, 8);      // 16-lane group sum = u[n]
                const bool dead = (n >= N_) || ((mk >> n) & 1ull);
                float w = dead ? 0.f : __expf(part);
                l += w;
#pragma unroll
                for (int j = 0; j < 8; ++j) a[j] += w * c[j];
            }
            // cross-group combine (once per phase)
#pragma unroll
            for (int mmk = 16; mmk < 64; mmk <<= 1) {
                l += __shfl_xor(l, mmk);
#pragma unroll
                for (int j = 0; j < 8; ++j) a[j] += __shfl_xor(a[j], mmk);
            }
            float inv = 1.f / l;
            if (nq == 0) {
                float4 o1 = {a[0] * inv, a[1] * inv, a[2] * inv, a[3] * inv};
                float4 o2 = {a[4] * inv, a[5] * inv, a[6] * inv, a[7] * inv};
                *(float4*)&sU[2048 + gW * 128 + dh * 8]     = o1;
                *(float4*)&sU[2048 + gW * 128 + dh * 8 + 4] = o2;
            }
        }
        __syncthreads();

        // ---- P5: qp GEMV (+ e_p prefetch for P6 issued first) ----
        float4 ppA0 = *(const float4*)&epb[(size_t)nq * 128];
        float4 ppB0 = *(const float4*)&epb[(size_t)nq * 128 + 4];
        float4 ppA1 = *(const float4*)&epb[(size_t)(4 + nq) * 128];
        float4 ppB1 = *(const float4*)&epb[(size_t)(4 + nq) * 128 + 4];
        if (use_t) {
            const int d  = tid & 127;
            const int gh = tid >> 7;
            const int g0 = gh * 2;
            const float* wq = pqT + d;
            float a0 = 0.f, a1 = 0.f;
#pragma unroll 4
            for (int e = 0; e < 128; e += 4) {
                float w0 = wq[(e + 0) * 128], w1 = wq[(e + 1) * 128];
                float w2 = wq[(e + 2) * 128], w3 = wq[(e + 3) * 128];
                float4 hA = *(const float4*)&sU[2048 + g0 * 128 + e];
                float4 hB = *(const float4*)&sU[2048 + (g0 + 1) * 128 + e];
                a0 += w0 * hA.x + w1 * hA.y + w2 * hA.z + w3 * hA.w;
                a1 += w0 * hB.x + w1 * hB.y + w2 * hB.z + w3 * hB.w;
            }
            sU[g0 * 128 + d]       = a0 + sPbq[d];
            sU[(g0 + 1) * 128 + d] = a1 + sPbq[d];
        } else {
            const int d  = tid & 127;
            const int gh = tid >> 7;
            const int g0 = gh * 2;
            const float* wr = pWq + (size_t)d * 128;
            float a0 = 0.f, a1 = 0.f;
            for (int e = 0; e < 128; e += 16) {
                float4 w4[4];
#pragma unroll
                for (int q = 0; q < 4; ++q) w4[q] = *(const float4*)&wr[e + 4 * q];
#pragma unroll
                for (int q = 0; q < 4; ++q) {
                    float4 hA = *(const float4*)&sU[2048 + g0 * 128 + e + 4 * q];
                    float4 hB = *(const float4*)&sU[2048 + (g0 + 1) * 128 + e + 4 * q];
                    a0 += w4[q].x * hA.x + w4[q].y * hA.y + w4[q].z * hA.z + w4[q].w * hA.w;
                    a1 += w4[q].x * hB.x + w4[q].y * hB.y + w4[q].z * hB.z + w4[q].w * hB.w;
                }
            }
            sU[g0 * 128 + d]       = a0 + sPbq[d];
            sU[(g0 + 1) * 128 + d] = a1 + sPbq[d];
        }
        __syncthreads();

        // ---- P6: pointer scores 4-rows-per-iter, then log_softmax, argmax, MLP ----
        {
            const int b = b0 + gW;
            const unsigned long long mk = sMaskC[gW];
            {
                float qpv[8], pvv[8];
                *(float4*)&qpv[0] = *(const float4*)&sU[gW * 128 + dh * 8];
                *(float4*)&qpv[4] = *(const float4*)&sU[gW * 128 + dh * 8 + 4];
                *(float4*)&pvv[0] = *(const float4*)&sPv[dh * 8];
                *(float4*)&pvv[4] = *(const float4*)&sPv[dh * 8 + 4];
#pragma unroll
                for (int blk = 0; blk < NB4_; ++blk) {
                    const int n = blk * 4 + nq;
                    const int nn = (n < N_) ? n : (N_ - 1);
                    float4 cA, cB;
                    if (blk == 0)      { cA = ppA0; cB = ppB0; }
                    else if (blk == 1) { cA = ppA1; cB = ppB1; }
                    else {
                        cA = *(const float4*)&epb[(size_t)nn * 128];
                        cB = *(const float4*)&epb[(size_t)nn * 128 + 4];
                    }
                    float c[8] = {cA.x, cA.y, cA.z, cA.w, cB.x, cB.y, cB.z, cB.w};
                    float part = 0.f;
#pragma unroll
                    for (int j = 0; j < 8; ++j) part += pvv[j] * ftanh_(qpv[j] + c[j]);
                    part += __shfl_xor(part, 1);
                    part += __shfl_xor(part, 2);
                    part += __shfl_xor(part, 4);
                    part += __shfl_xor(part, 8);
                    if (dh == 0 && n < N_) {
                        float tl = ((mk >> n) & 1ull) ? NEGV : 10.0f * ftanh_(part);
                        sLg[gW][n] = tl;    // within-wave staging; regathered below
                    }
                }
            }
            const bool active = lane < N_;
            float lgv = sLg[gW][lane];                 // lane=n regather (same wave wrote)
            float logit = active ? lgv : -__builtin_inff();
            // log-softmax over lanes
            float mx = logit;
#pragma unroll
            for (int mm = 1; mm < 64; mm <<= 1) mx = fmaxf(mx, __shfl_xor(mx, mm));
            float ex = active ? __expf(logit - mx) : 0.f;
            float s = wsum_(ex);
            float lse = mx + __logf(s);
            if (active)
                __builtin_nontemporal_store(logit - lse,
                    &outp[(size_t)b * (N_ * N_) + t * N_ + lane]);
            // argmax, first-index tie-break (matches jnp.argmax)
            float av = logit; int ai = active ? lane : (N_ - 1);
#pragma unroll
            for (int mm = 1; mm < 64; mm <<= 1) {
                float ov = __shfl_xor(av, mm);
                int   oi = __shfl_xor(ai, mm);
                bool take = (ov > av) || (ov == av && oi < ai);
                av = take ? ov : av;
                ai = take ? oi : ai;
            }
            const int idx = ai;
            // time-prediction MLP: lane = hidden unit j (TPH_ == 64)
            const int lastv = sLast[gW];
            const float* Vl = V + ((size_t)b * N_ + lastv) * DV_;
            const float* Vi = V + ((size_t)b * N_ + idx) * DV_;
            float hacc = tpb1[lane];
#pragma unroll
            for (int k = 0; k < 8; ++k)  hacc += Vl[k] * tpW1[k * 64 + lane];
#pragma unroll
            for (int k = 0; k < 8; ++k)  hacc += Vi[k] * tpW1[(8 + k) * 64 + lane];
#pragma unroll
            for (int k = 0; k < 4; ++k)  hacc += sSF[gW][k] * tpW1[(16 + k) * 64 + lane];
#pragma unroll
            for (int k = 0; k < 20; ++k) hacc += step_table[t * SE_ + k] * tpW1[(20 + k) * 64 + lane];
            hacc = fmaxf(hacc, 0.f);
            float pred = wsum_(hacc * tpW2[lane]) + tpb2[0];
            // next decoder input x2 = context_update[idx, b]
            const float* xrow = cu + ((size_t)idx * B_ + b) * D_;
            sX[gW][lane]      = xrow[lane];
            sX[gW][64 + lane] = xrow[64 + lane];
            if (lane == 0) {
                __builtin_nontemporal_store((float)idx,
                    &outp[(size_t)(B_ * N_) * N_ + (size_t)b * N_ + t]);
                __builtin_nontemporal_store(pred,
                    &outp[(size_t)(B_ * N_) * N_ + (size_t)(B_ * N_) + (size_t)b * N_ + t]);
                __builtin_nontemporal_store(pred,
                    &outp[(size_t)(B_ * N_) * N_ + 2 * (size_t)(B_ * N_) + (size_t)b * N_ + t]);
                sPrev[gW] = idx;
                sLast[gW] = idx;
            }
        }
        __syncthreads();
    }
}

extern "C" void kernel_launch(void* const* d_in, const int* in_sizes, int n_in,
                              void* d_out, int out_size, void* d_ws, size_t ws_size,
                              hipStream_t stream)
{
    const float* dec   = (const float*)d_in[0];
    const float* h0    = (const float*)d_in[1];
    const float* c0    = (const float*)d_in[2];
    const unsigned char* vmask = (const unsigned char*)d_in[3];
    const int*   sidx  = (const int*)d_in[4];
    const float* V     = (const float*)d_in[5];
    // d_in[6] b_E, d_in[7] b_E_abs, d_in[9] H_update: unused by reference
    const float* cu    = (const float*)d_in[8];
    const float* sfea  = (const float*)d_in[10];
    const float* W_ih  = (const float*)d_in[11];
    const float* W_hh  = (const float*)d_in[12];
    const float* b_ih  = (const float*)d_in[13];
    const float* b_hh  = (const float*)d_in[14];
    const float* gWq   = (const float*)d_in[15];
    const float* gbq   = (const float*)d_in[16];
    const float* gWr   = (const float*)d_in[17];
    const float* gbr   = (const float*)d_in[18];
    const float* gv    = (const float*)d_in[19];
    const float* pWq   = (const float*)d_in[20];
    const float* pbq   = (const float*)d_in[21];
    const float* pWr   = (const float*)d_in[22];
    const float* pbr   = (const float*)d_in[23];
    const float* pv    = (const float*)d_in[24];
    const float* stept = (const float*)d_in[25];
    const float* tpW1  = (const float*)d_in[26];
    const float* tpb1  = (const float*)d_in[27];
    const float* tpW2  = (const float*)d_in[28];
    const float* tpb2  = (const float*)d_in[29];

    const size_t EG = (size_t)B_ * N_ * D_;          // 26,214,400 floats
    float* e_g = (float*)d_ws;
    float* e_p = e_g + EG;

    // Transposed weights appended after e_p (needs +640 KB of ws)
    float* wtI = e_p + EG;
    float* wtH = wtI + 512 * 128;
    float* gqT = wtH + 512 * 128;
    float* pqT = gqT + 128 * 128;
    const size_t need = (2 * EG + 2 * (512 * 128) + 2 * (128 * 128)) * sizeof(float);
    const int use_t = (ws_size >= need) ? 1 : 0;

    // Precompute fixed attention keys (step-invariant)
    proj_kernel<<<dim3(1024), 256, 0, stream>>>(gWr, gbr, cu, e_g);
    proj_kernel<<<dim3(1024), 256, 0, stream>>>(pWr, pbr, cu, e_p);
    if (use_t) {
        transpose_kernel<<<dim3(256), 256, 0, stream>>>(W_ih, wtI, 512, 128);
        transpose_kernel<<<dim3(256), 256, 0, stream>>>(W_hh, wtH, 512, 128);
        transpose_kernel<<<dim3(64),  256, 0, stream>>>(gWq,  gqT, 128, 128);
        transpose_kernel<<<dim3(64),  256, 0, stream>>>(pWq,  pqT, 128, 128);
    }
    // Persistent 50-step decode: 256 blocks x 1024 threads, 16 batch rows/block
    decode_kernel<<<dim3(NBLK), 1024, 0, stream>>>(
        dec, h0, c0, vmask, sidx, V, cu, sfea,
        W_ih, W_hh, b_ih, b_hh,
        gWq, gbq, gv, pWq, pbq, pv,
        stept, tpW1, tpb1, tpW2, tpb2,
        e_g, e_p, wtI, wtH, gqT, pqT, use_t, (float*)d_out);
}